// Round 1
// 488.092 us; speedup vs baseline: 1.2239x; 1.2239x over previous
//
#include <hip/hip_runtime.h>
#include <hip/hip_bf16.h>

#define N_NODES 30000
#define N_EDGES 120000
#define NGRAPH  512
#define N2      15000
#define N3      7500
#define NC      10
#define TN      4            // source nodes per tile in k4_fused
#define NTILES  (N2 / TN)    // 3750
#define KTOT    26           // 25 t-rows + 1 bias row

typedef __hip_bfloat16 bf16;

__device__ __forceinline__ float lo(const float* p, int i) { return p[i]; }
__device__ __forceinline__ float lo(const bf16* p, int i) { return __bfloat162float(p[i]); }
__device__ __forceinline__ void sto(float* p, int i, float v) { p[i] = v; }
__device__ __forceinline__ void sto(bf16* p, int i, float v) { p[i] = __float2bfloat16(v); }
__device__ __forceinline__ float elu(float x) { return x > 0.f ? x : expm1f(x); }
template <typename T> __host__ __device__ constexpr int want_flag() { return sizeof(T) == 4 ? 1 : 0; }

// workspace layout (float offsets). Zero-initialized region first.
#define A1_OFF 0            // aggr1: N*32  = 960000 ; later reused as h2 (N2*64 = 960000)
#define C1_OFF 960000       // cnt1:  N     = 30000
#define A2_OFF 990000       // aggr2: N2*64 = 960000
#define C2_OFF 1950000      // cnt2:  N2    = 15000
#define GS_OFF 1965000      // gsum:  G*64  = 32768
#define GC_OFF 1997768      // gcnt:  G     = 512
#define MV_OFF 1998280      // maxv (uint bits) = 1
#define DEG_OFF 1998281     // per-tile edge count (int): NTILES = 3750
#define ZERO_FLOATS 2002031
#define X2_OFF 2002031      // x2:   N2*32 = 480000
#define P2_OFF 2482031      // pos2: N2*2  = 30000
#define CT_OFF 2512031      // cart: E*2   = 240000
#define OFF_OFF 2752031     // tile offsets (int): NTILES+1 = 3751
#define CUR_OFF 2755782     // placement cursor (int): NTILES = 3750
#define ES_OFF  2759532     // source-sorted edge ids (int): E = 120000
#define FLAG_OFF 2879532    // dtype flag (int): 1 = fp32 inputs, 0 = bf16 inputs
#define H2_OFF A1_OFF       // h2 overlays aggr1 (dead after k2)
// total = 2879533 floats ≈ 11.5 MB

// ---------------- dtype detector: bf16-view of fp32 data shows |v|>1e3 or NaN
__global__ __launch_bounds__(256) void k0_detect(const void* x, const void* ea, int* flag) {
  const bf16* xb = (const bf16*)x;
  const bf16* eb = (const bf16*)ea;
  int tid = threadIdx.x;
  float a = __bfloat162float(xb[tid]);
  float b = __bfloat162float(eb[tid]);
  int bad = (!(fabsf(a) < 1e3f)) || (!(fabsf(b) < 1e3f));  // catches NaN/Inf too
  unsigned long long m = __ballot(bad);
  __shared__ int anyb[4];
  int w = tid >> 6;
  if ((tid & 63) == 0) anyb[w] = (m != 0ULL) ? 1 : 0;
  __syncthreads();
  if (tid == 0) flag[0] = (anyb[0] | anyb[1] | anyb[2] | anyb[3]);
}

// ---------------- conv1 edge kernel
template <typename T>
__global__ __launch_bounds__(256) void k1_edge1(
    const int* __restrict__ flag,
    const T* __restrict__ x, const T* __restrict__ ea, const int* __restrict__ ei,
    const T* __restrict__ w1a, const T* __restrict__ b1a,
    const T* __restrict__ w1b, const T* __restrict__ b1b,
    float* __restrict__ aggr1, float* __restrict__ cnt1) {
  if (flag[0] != want_flag<T>()) return;
  __shared__ float w1a_l[50];
  __shared__ float b1a_l[25];
  __shared__ __align__(16) float w1b_l[25 * 32];
  __shared__ __align__(16) float b1b_l[32];
  int tid = threadIdx.x;
  for (int j = tid; j < 50; j += 256) w1a_l[j] = lo(w1a, j);
  for (int j = tid; j < 25; j += 256) b1a_l[j] = lo(b1a, j);
  for (int j = tid; j < 800; j += 256) w1b_l[j] = lo(w1b, j);
  for (int j = tid; j < 32; j += 256) b1b_l[j] = lo(b1b, j);
  __syncthreads();
  int e = blockIdx.x * 256 + tid;
  if (e >= N_EDGES) return;
  float a0 = lo(ea, 2 * e), a1v = lo(ea, 2 * e + 1);
  float t[25];
#pragma unroll
  for (int k = 0; k < 25; ++k)
    t[k] = fmaxf(a0 * w1a_l[k] + a1v * w1a_l[25 + k] + b1a_l[k], 0.f);
  int row = ei[e], col = ei[N_EDGES + e];
  float xv = lo(x, row);
  const float4* w1b4 = (const float4*)w1b_l;
  const float4* b1b4 = (const float4*)b1b_l;
  float* dst = aggr1 + col * 32;
#pragma unroll
  for (int o4 = 0; o4 < 8; ++o4) {
    float4 w = b1b4[o4];
#pragma unroll
    for (int k = 0; k < 25; ++k) {
      float4 q = w1b4[k * 8 + o4];
      w.x += t[k] * q.x; w.y += t[k] * q.y; w.z += t[k] * q.z; w.w += t[k] * q.w;
    }
    atomicAdd(dst + o4 * 4 + 0, xv * w.x);
    atomicAdd(dst + o4 * 4 + 1, xv * w.y);
    atomicAdd(dst + o4 * 4 + 2, xv * w.z);
    atomicAdd(dst + o4 * 4 + 3, xv * w.w);
  }
  atomicAdd(cnt1 + col, 1.f);
}

// ---------------- node update 1 + elu + pair max-pool + pos mean-pool
template <typename T>
__global__ __launch_bounds__(256) void k2_node1(
    const int* __restrict__ flag,
    const T* __restrict__ x, const T* __restrict__ pos,
    const T* __restrict__ root1, const T* __restrict__ bias1,
    const float* __restrict__ aggr1, const float* __restrict__ cnt1,
    float* __restrict__ x2, float* __restrict__ pos2) {
  if (flag[0] != want_flag<T>()) return;
  int idx = blockIdx.x * 256 + threadIdx.x;
  if (idx >= N2 * 32) return;
  int m = idx >> 5, o = idx & 31;
  int n0 = 2 * m, n1 = 2 * m + 1;
  float r = lo(root1, o), bs = lo(bias1, o);
  float c0 = fmaxf(cnt1[n0], 1.f), c1 = fmaxf(cnt1[n1], 1.f);
  float h0 = elu(aggr1[n0 * 32 + o] / c0 + lo(x, n0) * r + bs);
  float h1 = elu(aggr1[n1 * 32 + o] / c1 + lo(x, n1) * r + bs);
  x2[idx] = fmaxf(h0, h1);
  if (o < 2) pos2[m * 2 + o] = 0.5f * (lo(pos, n0 * 2 + o) + lo(pos, n1 * 2 + o));
}

// ---------------- cart + global abs-max (fp32 intermediates only; no dtype dep)
__global__ __launch_bounds__(256) void k3_cart(
    const int* __restrict__ ei, const float* __restrict__ pos2,
    float* __restrict__ cart, unsigned int* __restrict__ maxv) {
  int e = blockIdx.x * 256 + threadIdx.x;
  float m = 0.f;
  if (e < N_EDGES) {
    int r2 = ei[e] >> 1, c2 = ei[N_EDGES + e] >> 1;
    float cx = 0.f, cy = 0.f;
    if (r2 != c2) {
      cx = pos2[2 * c2] - pos2[2 * r2];
      cy = pos2[2 * c2 + 1] - pos2[2 * r2 + 1];
    }
    cart[2 * e] = cx;
    cart[2 * e + 1] = cy;
    m = fmaxf(fabsf(cx), fabsf(cy));
  }
#pragma unroll
  for (int s = 32; s > 0; s >>= 1)
    m = fmaxf(m, __shfl_xor(m, s, 64));
  __shared__ float wm[4];
  int lane = threadIdx.x & 63, wid = threadIdx.x >> 6;
  if (lane == 0) wm[wid] = m;
  __syncthreads();
  if (threadIdx.x == 0) {
    float mm = fmaxf(fmaxf(wm[0], wm[1]), fmaxf(wm[2], wm[3]));
    atomicMax(maxv, __float_as_uint(mm));
  }
}

// ---------------- CSR-by-source-tile build (dtype-free, depends only on ei)
__global__ __launch_bounds__(256) void kc_deg(const int* __restrict__ ei, int* __restrict__ deg) {
  int e = blockIdx.x * 256 + threadIdx.x;
  if (e >= N_EDGES) return;
  int r2 = ei[e] >> 1, c2 = ei[N_EDGES + e] >> 1;
  if (r2 != c2) atomicAdd(deg + (r2 >> 2), 1);
}

__global__ __launch_bounds__(256) void kc_scan(const int* __restrict__ deg,
                                               int* __restrict__ off, int* __restrict__ cur) {
  __shared__ int buf[256];
  __shared__ int carry;
  int tid = threadIdx.x;
  if (tid == 0) carry = 0;
  __syncthreads();
  for (int base = 0; base < NTILES; base += 256) {
    int i = base + tid;
    int v = (i < NTILES) ? deg[i] : 0;
    buf[tid] = v;
    __syncthreads();
#pragma unroll
    for (int s = 1; s < 256; s <<= 1) {
      int t = (tid >= s) ? buf[tid - s] : 0;
      __syncthreads();
      buf[tid] += t;
      __syncthreads();
    }
    int excl = carry + buf[tid] - v;
    if (i < NTILES) { off[i] = excl; cur[i] = excl; }
    int tot = buf[255];
    __syncthreads();
    if (tid == 0) carry += tot;
    __syncthreads();
  }
  if (tid == 0) off[NTILES] = carry;
}

__global__ __launch_bounds__(256) void kc_place(const int* __restrict__ ei,
                                                int* __restrict__ cur, int* __restrict__ es) {
  int e = blockIdx.x * 256 + threadIdx.x;
  if (e >= N_EDGES) return;
  int r2 = ei[e] >> 1, c2 = ei[N_EDGES + e] >> 1;
  if (r2 != c2) {
    int p = atomicAdd(cur + (r2 >> 2), 1);
    es[p] = e;
  }
}

// ---------------- conv2, factorized: per-tile Y = x2 @ w2b' in LDS, then per-edge
// msg[o] = sum_k t'[k] * Y[src][k][o]   (t'[25] = 1, Y row 25 = bias contraction)
template <typename T>
__global__ __launch_bounds__(256) void k4_fused(
    const int* __restrict__ flag,
    const int* __restrict__ ei, const float* __restrict__ cart, const float* __restrict__ maxv_f,
    const float* __restrict__ x2,
    const T* __restrict__ w2a, const T* __restrict__ b2a,
    const T* __restrict__ w2b, const T* __restrict__ b2b,
    const int* __restrict__ off, const int* __restrict__ es,
    float* __restrict__ aggr2, float* __restrict__ cnt2) {
  if (flag[0] != want_flag<T>()) return;
  __shared__ float Y[TN][KTOT][64];   // 26624 B
  __shared__ float xl[TN][32];
  __shared__ float w2a_l[50];
  __shared__ float b2a_l[25];
  int tid = threadIdx.x;
  int tile = blockIdx.x;
  int n0 = tile * TN;
  if (tid < TN * 32) xl[tid >> 5][tid & 31] = x2[n0 * 32 + tid];
  if (tid >= 128 && tid < 178) w2a_l[tid - 128] = lo(w2a, tid - 128);
  if (tid >= 192 && tid < 217) b2a_l[tid - 192] = lo(b2a, tid - 192);
  __syncthreads();
  int w = tid >> 6, o = tid & 63;
  // phase 1: Y[nl][kk][o] = sum_i xl[nl][i] * w2b'[kk][i][o]; row KTOT-1 from b2b
  for (int kk = w; kk < KTOT; kk += 4) {
    const T* src = (kk < 25) ? (w2b + kk * 2048) : b2b;
    float a0 = 0.f, a1 = 0.f, a2 = 0.f, a3 = 0.f;
#pragma unroll 8
    for (int i = 0; i < 32; ++i) {
      float q = lo(src, i * 64 + o);
      a0 += xl[0][i] * q;
      a1 += xl[1][i] * q;
      a2 += xl[2][i] * q;
      a3 += xl[3][i] * q;
    }
    Y[0][kk][o] = a0; Y[1][kk][o] = a1; Y[2][kk][o] = a2; Y[3][kk][o] = a3;
  }
  __syncthreads();
  // phase 2: edges of this source tile (one warp per edge, lane = output channel)
  float inv = 0.5f / maxv_f[0];
  int ebeg = off[tile], eend = off[tile + 1];
  for (int j = ebeg + w; j < eend; j += 4) {
    int e = es[j];
    int r2 = ei[e] >> 1;
    int c2 = ei[N_EDGES + e] >> 1;
    int nl = r2 & (TN - 1);
    float ax = cart[2 * e] * inv + 0.5f;
    float ay = cart[2 * e + 1] * inv + 0.5f;
    float acc = Y[nl][25][o];
#pragma unroll
    for (int k = 0; k < 25; ++k) {
      float t = fmaxf(ax * w2a_l[k] + ay * w2a_l[25 + k] + b2a_l[k], 0.f);
      acc += t * Y[nl][k][o];
    }
    atomicAdd(aggr2 + c2 * 64 + o, acc);
    if (o == 0) atomicAdd(cnt2 + c2, 1.f);
  }
}

// ---------------- node update 2 + elu
template <typename T>
__global__ __launch_bounds__(256) void k5_node2(
    const int* __restrict__ flag,
    const float* __restrict__ aggr2, const float* __restrict__ cnt2,
    const float* __restrict__ x2,
    const T* __restrict__ root2, const T* __restrict__ bias2,
    float* __restrict__ h2) {
  if (flag[0] != want_flag<T>()) return;
  int idx = blockIdx.x * 256 + threadIdx.x;
  if (idx >= N2 * 64) return;
  int n = idx >> 6, o = idx & 63;
  float s = aggr2[idx] / fmaxf(cnt2[n], 1.f) + lo(bias2, o);
  const float* xr = x2 + n * 32;
#pragma unroll
  for (int i = 0; i < 32; ++i) s += xr[i] * lo(root2, i * 64 + o);
  h2[idx] = elu(s);
}

// ---------------- pair max-pool 2 + per-graph sum/count
__global__ __launch_bounds__(256) void k6_pool2(
    const float* __restrict__ h2, const int* __restrict__ batch,
    float* __restrict__ gsum, float* __restrict__ gcnt) {
  int idx = blockIdx.x * 256 + threadIdx.x;
  if (idx >= N3 * 64) return;
  int m = idx >> 6, o = idx & 63;
  float v = fmaxf(h2[(2 * m) * 64 + o], h2[(2 * m + 1) * 64 + o]);
  int b = batch[4 * m];
  atomicAdd(gsum + b * 64 + o, v);
  if (o == 0) atomicAdd(gcnt + b, 1.f);
}

// ---------------- graph mean -> fc1 -> elu -> fc2 -> log_softmax
template <typename T>
__global__ __launch_bounds__(128) void k7_head(
    const int* __restrict__ flag,
    const float* __restrict__ gsum, const float* __restrict__ gcnt,
    const T* __restrict__ fc1_w, const T* __restrict__ fc1_b,
    const T* __restrict__ fc2_w, const T* __restrict__ fc2_b,
    T* __restrict__ out) {
  if (flag[0] != want_flag<T>()) return;
  __shared__ float gv[64];
  __shared__ float h1s[128];
  __shared__ float zs[NC];
  __shared__ float lse;
  int g = blockIdx.x, tid = threadIdx.x;
  if (tid < 64) gv[tid] = gsum[g * 64 + tid] / fmaxf(gcnt[g], 1.f);
  __syncthreads();
  float a = lo(fc1_b, tid);
#pragma unroll 8
  for (int o = 0; o < 64; ++o) a += gv[o] * lo(fc1_w, o * 128 + tid);
  h1s[tid] = elu(a);
  __syncthreads();
  if (tid < NC) {
    float s = lo(fc2_b, tid);
    for (int j = 0; j < 128; ++j) s += h1s[j] * lo(fc2_w, j * NC + tid);
    zs[tid] = s;
  }
  __syncthreads();
  if (tid == 0) {
    float m = -1e30f;
    for (int c = 0; c < NC; ++c) m = fmaxf(m, zs[c]);
    float s = 0.f;
    for (int c = 0; c < NC; ++c) s += expf(zs[c] - m);
    lse = m + logf(s);
  }
  __syncthreads();
  if (tid < NC) sto(out, g * NC + tid, zs[tid] - lse);
}

template <typename T>
static void stage1(void* const* d_in, float* ws, hipStream_t stream) {
  const T* x     = (const T*)d_in[0];
  const T* ea    = (const T*)d_in[1];
  const T* pos   = (const T*)d_in[2];
  const T* w1a   = (const T*)d_in[3];
  const T* b1a   = (const T*)d_in[4];
  const T* w1b   = (const T*)d_in[5];
  const T* b1b   = (const T*)d_in[6];
  const T* root1 = (const T*)d_in[7];
  const T* bias1 = (const T*)d_in[8];
  const int* ei   = (const int*)d_in[19];
  const int* flag = (const int*)(ws + FLAG_OFF);

  k1_edge1<T><<<(N_EDGES + 255) / 256, 256, 0, stream>>>(
      flag, x, ea, ei, w1a, b1a, w1b, b1b, ws + A1_OFF, ws + C1_OFF);
  k2_node1<T><<<(N2 * 32 + 255) / 256, 256, 0, stream>>>(
      flag, x, pos, root1, bias1, ws + A1_OFF, ws + C1_OFF, ws + X2_OFF, ws + P2_OFF);
}

template <typename T>
static void stage2(void* const* d_in, float* ws, hipStream_t stream) {
  const T* w2a   = (const T*)d_in[9];
  const T* b2a   = (const T*)d_in[10];
  const T* w2b   = (const T*)d_in[11];
  const T* b2b   = (const T*)d_in[12];
  const T* root2 = (const T*)d_in[13];
  const T* bias2 = (const T*)d_in[14];
  const int* ei   = (const int*)d_in[19];
  const int* flag = (const int*)(ws + FLAG_OFF);

  k4_fused<T><<<NTILES, 256, 0, stream>>>(
      flag, ei, ws + CT_OFF, ws + MV_OFF, ws + X2_OFF, w2a, b2a, w2b, b2b,
      (const int*)(ws + OFF_OFF), (const int*)(ws + ES_OFF),
      ws + A2_OFF, ws + C2_OFF);
  k5_node2<T><<<(N2 * 64 + 255) / 256, 256, 0, stream>>>(
      flag, ws + A2_OFF, ws + C2_OFF, ws + X2_OFF, root2, bias2, ws + H2_OFF);
}

extern "C" void kernel_launch(void* const* d_in, const int* in_sizes, int n_in,
                              void* d_out, int out_size, void* d_ws, size_t ws_size,
                              hipStream_t stream) {
  float* ws = (float*)d_ws;
  const int* flag = (const int*)(ws + FLAG_OFF);
  const int* ei = (const int*)d_in[19];
  const int* batch = (const int*)d_in[20];

  k0_detect<<<1, 256, 0, stream>>>(d_in[0], d_in[1], (int*)(ws + FLAG_OFF));
  hipMemsetAsync(d_ws, 0, (size_t)ZERO_FLOATS * 4, stream);

  // CSR-by-source-tile build (dtype-free): deg -> offsets -> placement
  kc_deg<<<(N_EDGES + 255) / 256, 256, 0, stream>>>(ei, (int*)(ws + DEG_OFF));
  kc_scan<<<1, 256, 0, stream>>>((const int*)(ws + DEG_OFF), (int*)(ws + OFF_OFF),
                                 (int*)(ws + CUR_OFF));
  kc_place<<<(N_EDGES + 255) / 256, 256, 0, stream>>>(ei, (int*)(ws + CUR_OFF),
                                                      (int*)(ws + ES_OFF));

  // conv1 + pool1 for both dtype variants (non-matching one early-returns)
  stage1<float>(d_in, ws, stream);
  stage1<bf16>(d_in, ws, stream);

  // cart/maxv: dtype-free, needs pos2 from whichever k2 ran -> after BOTH stage1s
  k3_cart<<<(N_EDGES + 255) / 256, 256, 0, stream>>>(
      ei, ws + P2_OFF, ws + CT_OFF, (unsigned int*)(ws + MV_OFF));

  // conv2 (factorized) + node update for both dtype variants
  stage2<float>(d_in, ws, stream);
  stage2<bf16>(d_in, ws, stream);

  // dtype-free tail: pool2, then dual head
  k6_pool2<<<(N3 * 64 + 255) / 256, 256, 0, stream>>>(
      ws + H2_OFF, batch, ws + GS_OFF, ws + GC_OFF);
  k7_head<float><<<NGRAPH, 128, 0, stream>>>(
      flag, ws + GS_OFF, ws + GC_OFF,
      (const float*)d_in[15], (const float*)d_in[16],
      (const float*)d_in[17], (const float*)d_in[18], (float*)d_out);
  k7_head<bf16><<<NGRAPH, 128, 0, stream>>>(
      flag, ws + GS_OFF, ws + GC_OFF,
      (const bf16*)d_in[15], (const bf16*)d_in[16],
      (const bf16*)d_in[17], (const bf16*)d_in[18], (bf16*)d_out);
}